// Round 11
// baseline (36.951 us; speedup 1.0000x reference)
//
#include <hip/hip_runtime.h>

// RecModel — round 11. Model (fits R5-R10): mlp time = load-use chain depth ×
// L2/L3 latency; invariant to waves & bytes. Fix: full-depth register prefetch
// — every GEMM1 operand issued at kernel entry (~41 independent loads/wave),
// one latency exposure total. Shape stays 1024x256 (best known). prep = R10.

using u16 = unsigned short;
typedef __attribute__((ext_vector_type(8))) short short8v;
typedef __attribute__((ext_vector_type(4))) short short4v;
typedef __attribute__((ext_vector_type(4))) float floatx4;

constexpr int W1_ELEMS = 13 * 8 * 64 * 8;    // 53248
constexpr int W2_ELEMS = 5 * 7 * 64 * 8;     // 17920
constexpr int EF_ELEMS = 1024 * 7 * 64 * 8;  // 3670016

__device__ __forceinline__ u16 f2bf(float f) {
  unsigned u = __float_as_uint(f);
  unsigned r = (u + 0x7fffu + ((u >> 16) & 1u)) >> 16;  // RN-even
  return (u16)r;
}
__device__ __forceinline__ float bf2f(u16 h) {
  return __uint_as_float(((unsigned)h) << 16);
}

// ---- prep: [0,35) weight frags | [35,3619) emb gather | [3619,4643) history ----
__global__ __launch_bounds__(256) void prep_kernel(
    const float* __restrict__ w1, const float* __restrict__ w2,
    const float* __restrict__ W, const int* __restrict__ sf,
    const int* __restrict__ hist, const float* __restrict__ dense,
    u16* __restrict__ w1h, u16* __restrict__ w2h,
    u16* __restrict__ ef, u16* __restrict__ hs) {
  const int b = blockIdx.x;
  const int tix = threadIdx.x;
  short8v z8 = {0, 0, 0, 0, 0, 0, 0, 0};

  if (b < 35) {
    int tid = b * 256 + tix;
    if (tid < 13 * 8 * 64) {  // fc1 frags
      int l = tid & 63;
      int g = tid >> 6;
      int kt = g & 7, nt = g >> 3;
      int n = nt * 16 + (l & 15);
      int kb = kt * 32 + (l >> 4) * 8;
      short8v h8;
#pragma unroll
      for (int e = 0; e < 8; ++e) {
        int k = kb + e;
        float v = (n < 200 && k < 241) ? w1[n * 241 + k] : 0.f;
        h8[e] = (short)f2bf(v);
      }
      *(short8v*)&w1h[tid * 8] = h8;
    } else if (tid < 13 * 8 * 64 + 5 * 7 * 64) {  // fc2 frags
      int t2 = tid - 13 * 8 * 64;
      int l = t2 & 63;
      int g = t2 >> 6;
      int kt = g % 7, nt = g / 7;
      int n = nt * 16 + (l & 15);
      int kb = kt * 32 + (l >> 4) * 8;
      short8v h8;
#pragma unroll
      for (int e = 0; e < 8; ++e) {
        int k = kb + e;
        float v = (k < 200) ? w2[n * 200 + k] : 0.f;
        h8[e] = (short)f2bf(v);
      }
      *(short8v*)&w2h[t2 * 8] = h8;
    }
  } else if (b < 3619) {
    // embedding gather: one thread per (t, batch, q)
    int g = (b - 35) * 256 + tix;  // < 917504
    int t = g >> 16;
    int bb = (g >> 2) & 16383;
    int q = g & 3;
    int idx = sf[bb * 14 + t] + 1;  // [1,100000]
    floatx4 v4 = *(const floatx4*)(W + ((size_t)t * 100001 + (size_t)idx) * 16 + q * 4);
    short4v h4;
#pragma unroll
    for (int d = 0; d < 4; ++d) h4[d] = (short)f2bf(v4[d]);
    int k0 = t * 16 + q * 4;  // kt 0..6
    int kt = k0 >> 5, kg = (k0 >> 3) & 3, e0 = k0 & 7;
    int tile = bb >> 4, r = bb & 15;
    *(short4v*)&ef[((tile * 7 + kt) * 64 + kg * 16 + r) * 8 + e0] = h4;
  } else {
    // history: 16 thr/row (q dim-quad x s 4-way split), fp32 W, 16 rows/block
    int tile = b - 3619;
    int row0 = tile * 16;
    int r = tix >> 4, rem = tix & 15, q = rem & 3, s = rem >> 2;
    const int* hp = hist + (row0 + r) * 50;
    float a0 = 0.f, a1 = 0.f, a2 = 0.f, a3 = 0.f;
#pragma unroll
    for (int hh = 0; hh < 12; ++hh) {  // h = s + 4*hh (constant trip)
      int idx = hp[s + hh * 4] + 1;    // row 0 never hit
      floatx4 p = *(const floatx4*)(W + (size_t)idx * 16 + q * 4);
      a0 += p[0];
      a1 += p[1];
      a2 += p[2];
      a3 += p[3];
    }
    if (s < 2) {  // tail h = 48+s
      int idx = hp[48 + s] + 1;
      floatx4 p = *(const floatx4*)(W + (size_t)idx * 16 + q * 4);
      a0 += p[0];
      a1 += p[1];
      a2 += p[2];
      a3 += p[3];
    }
    a0 += __shfl_xor(a0, 4);
    a1 += __shfl_xor(a1, 4);
    a2 += __shfl_xor(a2, 4);
    a3 += __shfl_xor(a3, 4);
    a0 += __shfl_xor(a0, 8);
    a1 += __shfl_xor(a1, 8);
    a2 += __shfl_xor(a2, 8);
    a3 += __shfl_xor(a3, 8);
    if (s == 0) {
      float vals[4] = {a0, a1, a2, a3};
      short4v h4, l4;
#pragma unroll
      for (int d = 0; d < 4; ++d) {
        u16 hi = f2bf(vals[d]);
        h4[d] = (short)hi;
        l4[d] = (short)f2bf(vals[d] - bf2f(hi));
      }
      u16* ht = hs + (size_t)tile * 1024;
      int base = ((q >> 1) * 16 + r) * 8 + ((q * 4) & 7);
      *(short4v*)&ht[base] = h4;
      *(short4v*)&ht[512 + base] = l4;
      if (q == 0) {
        float dv = dense[row0 + r];
        u16 dh = f2bf(dv), dl = f2bf(dv - bf2f(dh));
        short8v dh8 = z8, dl8 = z8;
        dh8[0] = (short)dh;
        dl8[0] = (short)dl;
        *(short8v*)&ht[(32 + r) * 8] = dh8;  // k 240..247 (dense + pad)
        *(short8v*)&ht[512 + (32 + r) * 8] = dl8;
        *(short8v*)&ht[(48 + r) * 8] = z8;   // k 248..255 zero
        *(short8v*)&ht[512 + (48 + r) * 8] = z8;
      }
    }
  }
}

// ---- mlp: 1024 blocks x 256 thr, full-depth register prefetch ----
__global__ __launch_bounds__(256, 2) void mlp_kernel(
    const u16* __restrict__ ef, const u16* __restrict__ hs,
    const u16* __restrict__ w1h, const u16* __restrict__ w2h,
    const float* __restrict__ b1, const float* __restrict__ b2,
    const float* __restrict__ w3, const float* __restrict__ b3,
    float* __restrict__ out) {
  __shared__ u16 A2h[7 * 64 * 8], A2l[7 * 64 * 8];  // 7KB + 7KB
  __shared__ float o2[16 * 84];                     // 5.25KB

  const int tid = threadIdx.x;
  const int l = tid & 63;
  const int ntg = tid >> 6;  // wave id 0..3
  const int tile = blockIdx.x;
  const int row0 = tile * 16;
  short8v z8 = {0, 0, 0, 0, 0, 0, 0, 0};
  const int ntbase = (ntg == 0) ? 0 : 4 + 3 * (ntg - 1);
  const int ntcnt = (ntg == 0) ? 4 : 3;

  // ==== FULL-DEPTH prefetch: every GEMM1 operand, one latency exposure ====
  // A: kt=7 slab (hi/lo) from hs + kt 0..6 from ef  (9 loads)
  const u16* ht = hs + (size_t)tile * 1024;
  short8v a7h = *(const short8v*)&ht[l * 8];
  short8v a7l = *(const short8v*)&ht[512 + l * 8];
  short8v ga[7];
#pragma unroll
  for (int kt = 0; kt < 7; ++kt)
    ga[kt] = *(const short8v*)&ef[((tile * 7 + kt) * 64 + l) * 8];

  // B1: entire nt-slice x all 8 kt (24-32 loads)
  short8v b1r[4][8];
#pragma unroll
  for (int i = 0; i < 4; ++i) {
#pragma unroll
    for (int kt = 0; kt < 8; ++kt) {
      if (i < ntcnt)
        b1r[i][kt] = *(const short8v*)&w1h[(((ntbase + i) * 8 + kt) * 64 + l) * 8];
      else
        b1r[i][kt] = z8;
    }
  }

  // ---- GEMM1: pure register MFMA stream ----
  floatx4 acc[4];
#pragma unroll
  for (int i = 0; i < 4; ++i) acc[i] = (floatx4){0.f, 0.f, 0.f, 0.f};

#pragma unroll
  for (int kt = 0; kt < 8; ++kt) {
    short8v ah = (kt < 7) ? ga[kt] : a7h;
#pragma unroll
    for (int i = 0; i < 4; ++i) {
      if (i < ntcnt) {
        acc[i] = __builtin_amdgcn_mfma_f32_16x16x32_bf16(ah, b1r[i][kt], acc[i], 0, 0, 0);
        if (kt == 7)
          acc[i] = __builtin_amdgcn_mfma_f32_16x16x32_bf16(a7l, b1r[i][kt], acc[i], 0, 0, 0);
      }
    }
  }

  // B2 full prefetch (b1r dead -> registers reuse); consumed after barrier
  const bool dual = (ntg == 3);  // ntg3 also handles nt2=4
  short8v b2a[7], b2b[7];
#pragma unroll
  for (int kt = 0; kt < 7; ++kt) {
    b2a[kt] = *(const short8v*)&w2h[((ntg * 7 + kt) * 64 + l) * 8];
    b2b[kt] = dual ? *(const short8v*)&w2h[((4 * 7 + kt) * 64 + l) * 8] : z8;
  }

  // ---- epilogue1: bias+relu -> A2 frags (hi/lo) ----
#pragma unroll
  for (int i = 0; i < 4; ++i) {
    if (i < ntcnt) {
      int n = (ntbase + i) * 16 + (l & 15);
      float bias = (n < 200) ? b1[n] : 0.f;
      int kt2 = n >> 5, kg2 = (n >> 3) & 3, e = n & 7;
#pragma unroll
      for (int g = 0; g < 4; ++g) {
        float v = (n < 200) ? fmaxf(acc[i][g] + bias, 0.f) : 0.f;
        int m = (l >> 4) * 4 + g;
        u16 hi = f2bf(v), lo = f2bf(v - bf2f(hi));
        int pos = (kt2 * 64 + kg2 * 16 + m) * 8 + e;
        A2h[pos] = hi;
        A2l[pos] = lo;
      }
    }
  }
  if (ntg == 1 && l < 32) {  // zero k2 in [208,224)
    *(short8v*)&A2h[(6 * 64 + 32 + l) * 8] = z8;
    *(short8v*)&A2l[(6 * 64 + 32 + l) * 8] = z8;
  }
  __syncthreads();  // A2 complete

  // ---- GEMM2: A2 from LDS, B2 already in registers ----
  floatx4 acc2a = (floatx4){0.f, 0.f, 0.f, 0.f};
  floatx4 acc2b = (floatx4){0.f, 0.f, 0.f, 0.f};
#pragma unroll
  for (int kt = 0; kt < 7; ++kt) {
    short8v ah = *(const short8v*)&A2h[(kt * 64 + l) * 8];
    short8v al = *(const short8v*)&A2l[(kt * 64 + l) * 8];
    acc2a = __builtin_amdgcn_mfma_f32_16x16x32_bf16(ah, b2a[kt], acc2a, 0, 0, 0);
    acc2a = __builtin_amdgcn_mfma_f32_16x16x32_bf16(al, b2a[kt], acc2a, 0, 0, 0);
    if (dual) {
      acc2b = __builtin_amdgcn_mfma_f32_16x16x32_bf16(ah, b2b[kt], acc2b, 0, 0, 0);
      acc2b = __builtin_amdgcn_mfma_f32_16x16x32_bf16(al, b2b[kt], acc2b, 0, 0, 0);
    }
  }

  // ---- epilogue2: bias+relu -> o2 [16][84] ----
  {
    int n = ntg * 16 + (l & 15);
    float bias = b2[n];
#pragma unroll
    for (int g = 0; g < 4; ++g) {
      int r2 = (l >> 4) * 4 + g;
      o2[r2 * 84 + n] = fmaxf(acc2a[g] + bias, 0.f);
    }
    if (dual) {
      int n2 = 64 + (l & 15);
      float bias2 = b2[n2];
#pragma unroll
      for (int g = 0; g < 4; ++g) {
        int r2 = (l >> 4) * 4 + g;
        o2[r2 * 84 + n2] = fmaxf(acc2b[g] + bias2, 0.f);
      }
    }
  }
  __syncthreads();  // o2 complete

  // ---- fc3: 32 threads, one (row, out) pair each ----
  if (tid < 32) {
    int r = tid >> 1, o = tid & 1;
    float a = b3[o];
    const float* orow = &o2[r * 84];
    const float* wrow = &w3[o * 80];
#pragma unroll
    for (int j = 0; j < 80; j += 4) {
      floatx4 xv = *(const floatx4*)&orow[j];
      floatx4 wv4 = *(const floatx4*)&wrow[j];
      a += xv[0] * wv4[0] + xv[1] * wv4[1] + xv[2] * wv4[2] + xv[3] * wv4[3];
    }
    out[(row0 + r) * 2 + o] = a;
  }
}

extern "C" void kernel_launch(void* const* d_in, const int* in_sizes, int n_in,
                              void* d_out, int out_size, void* d_ws, size_t ws_size,
                              hipStream_t stream) {
  const int* sf = (const int*)d_in[0];
  const float* dense = (const float*)d_in[1];
  const int* hist = (const int*)d_in[2];
  const float* W = (const float*)d_in[3];
  const float* w1 = (const float*)d_in[4];
  const float* b1 = (const float*)d_in[5];
  const float* w2 = (const float*)d_in[6];
  const float* b2 = (const float*)d_in[7];
  const float* w3 = (const float*)d_in[8];
  const float* b3 = (const float*)d_in[9];
  float* out = (float*)d_out;

  u16* w1h = (u16*)d_ws;
  u16* w2h = w1h + W1_ELEMS;
  u16* ef = w2h + W2_ELEMS;
  u16* hs = ef + EF_ELEMS;  // 2 MB

  prep_kernel<<<dim3(35 + 3584 + 1024), dim3(256), 0, stream>>>(
      w1, w2, W, sf, hist, dense, w1h, w2h, ef, hs);
  mlp_kernel<<<dim3(1024), dim3(256), 0, stream>>>(ef, hs, w1h, w2h, b1, b2, w3, b3, out);
}